// Round 9
// baseline (251.651 us; speedup 1.0000x reference)
//
#include <hip/hip_runtime.h>
#include <hip/hip_bf16.h>
#include <math.h>

#define TSEQ 2048
#define NHQ 32
#define NHK 8
#define DH 128

typedef __attribute__((ext_vector_type(8))) short short8;
typedef __attribute__((ext_vector_type(4))) float f32x4;
typedef __attribute__((ext_vector_type(4))) short s16x4;

__device__ __forceinline__ short f2bf(float f) {
  union { float f; unsigned u; } v; v.f = f;
  unsigned r = v.u + 0x7fffu + ((v.u >> 16) & 1u);
  return (short)(r >> 16);
}

__device__ __forceinline__ f32x4 zero4() {
  f32x4 z; z[0] = 0.f; z[1] = 0.f; z[2] = 0.f; z[3] = 0.f; return z;
}

// async 16B global->LDS DMA (LDS dest wave-uniform base + lane*16).
__device__ __forceinline__ void async_cp16(const short* g, short* l) {
  __builtin_amdgcn_global_load_lds(
      (const __attribute__((address_space(1))) unsigned int*)g,
      (__attribute__((address_space(3))) unsigned int*)l, 16, 0, 0);
}

// ------------------------------------------------------------------
// prep+transpose fused (proven r7)
// ------------------------------------------------------------------
__global__ __launch_bounds__(256) void prep_transpose_kernel(
    const float* __restrict__ q, const float* __restrict__ k,
    const float* __restrict__ v, short* __restrict__ qkv,
    float* __restrict__ cosT, float* __restrict__ sinT,
    const float* __restrict__ Wq, const float* __restrict__ Wk,
    const float* __restrict__ Wv, const float* __restrict__ Wo,
    short* __restrict__ WqT, short* __restrict__ WkT,
    short* __restrict__ WvT, short* __restrict__ WoT) {
  __shared__ short tl[64][65];
  int bx = blockIdx.x, tid = threadIdx.x;
  if (bx < 1792) {
    int gid = bx * 256 + tid;
    if (gid < 393216) {
      int i4 = gid * 4;
      const float* src = (i4 < 524288) ? (q + i4)
                       : (i4 < 1048576 ? (k + i4 - 524288) : (v + i4 - 1048576));
      float f0 = src[0], f1 = src[1], f2 = src[2], f3 = src[3];
      s16x4 o; o[0] = f2bf(f0); o[1] = f2bf(f1); o[2] = f2bf(f2); o[3] = f2bf(f3);
      *(s16x4*)&qkv[i4] = o;
    } else if (gid < 458752) {
      int idx = (gid - 393216) * 4;
      int t = idx >> 7, d0 = idx & 127;
      float pos = (float)(8192 - TSEQ + t);
#pragma unroll
      for (int jj = 0; jj < 4; ++jj) {
        int d = d0 + jj;
        float inv = exp2f(-0.10381025296522977f * (float)d);
        float f = pos * inv;
        cosT[t * 128 + d] = cosf(f);
        sinT[t * 128 + d] = sinf(f);
      }
    }
    return;
  }
  int b = bx - 1792;
  const float* S; short* D; int K, N, tr, tc;
  if (b < 256)      { S = Wq; D = WqT; K = 256;  N = 4096; tr = b >> 6;        tc = b & 63; }
  else if (b < 320) { S = Wk; D = WkT; K = 256;  N = 1024; int t = b - 256; tr = t >> 4; tc = t & 15; }
  else if (b < 384) { S = Wv; D = WvT; K = 256;  N = 1024; int t = b - 320; tr = t >> 4; tc = t & 15; }
  else              { S = Wo; D = WoT; K = 4096; N = 256;  int t = b - 384; tr = t >> 2; tc = t & 3; }
  int k0 = tr * 64, n0 = tc * 64;
#pragma unroll
  for (int it = 0; it < 4; ++it) {
    int r = it * 16 + (tid >> 4), c = (tid & 15) * 4;
    const float* s = &S[(size_t)(k0 + r) * N + n0 + c];
    tl[r][c + 0] = f2bf(s[0]); tl[r][c + 1] = f2bf(s[1]);
    tl[r][c + 2] = f2bf(s[2]); tl[r][c + 3] = f2bf(s[3]);
  }
  __syncthreads();
#pragma unroll
  for (int it = 0; it < 4; ++it) {
    int rr = it * 16 + (tid >> 4), cc = (tid & 15) * 4;
    s16x4 o;
    o[0] = tl[cc + 0][rr]; o[1] = tl[cc + 1][rr];
    o[2] = tl[cc + 2][rr]; o[3] = tl[cc + 3][rr];
    *(s16x4*)&D[(size_t)(n0 + rr) * K + k0 + cc] = o;
  }
}

// ------------------------------------------------------------------
// proj (proven r7): DMA-staged dbuf, RoPE epilogue, Q pre-scaled.
// ------------------------------------------------------------------
#define SCALE 0.08838834764831845f

__global__ __launch_bounds__(256) void proj_kernel(
    const short* __restrict__ qkv,
    const short* __restrict__ WqT, const short* __restrict__ WkT,
    const short* __restrict__ WvT,
    const float* __restrict__ cosT, const float* __restrict__ sinT,
    short* __restrict__ Qr, short* __restrict__ Kr, short* __restrict__ Vt) {
  __shared__ __attribute__((aligned(16))) short As[2][64 * 64];
  __shared__ __attribute__((aligned(16))) short Bs[2][128 * 64];
  int tid = threadIdx.x, lane = tid & 63, w = tid >> 6;
  int i = lane & 15, grp = lane >> 4;
  int bh = blockIdx.y, r0 = blockIdx.x * 64;
  const short* X; const short* Wt; short* dst; int vmode = 0;
  float oscale = 1.0f;
  if (bh < 32)      { X = qkv;                Wt = WqT + bh * (128 * 256);        dst = Qr + (size_t)bh * TSEQ * DH; oscale = SCALE; }
  else if (bh < 40) { X = qkv + TSEQ * 256;   Wt = WkT + (bh - 32) * (128 * 256); dst = Kr + (size_t)(bh - 32) * TSEQ * DH; }
  else              { X = qkv + 2 * TSEQ * 256; Wt = WvT + (bh - 40) * (128 * 256); dst = Vt + (size_t)(bh - 40) * DH * TSEQ; vmode = 1; }

  const short* srcA[2];
#pragma unroll
  for (int j = 0; j < 2; ++j) {
    int ci = w * 128 + j * 64 + lane;
    int row = ci >> 3, c = ci & 7;
    srcA[j] = X + (size_t)(r0 + row) * 256 + ((c ^ (row & 7)) << 3);
  }
  const short* srcB[4];
#pragma unroll
  for (int j = 0; j < 4; ++j) {
    int ci = w * 256 + j * 64 + lane;
    int row = ci >> 3, c = ci & 7;
    srcB[j] = Wt + (size_t)row * 256 + ((c ^ (row & 7)) << 3);
  }
  auto stage = [&](int kc_, int bsel) {
#pragma unroll
    for (int j = 0; j < 2; ++j)
      async_cp16(srcA[j] + kc_ * 64, &As[bsel][(w * 128 + j * 64) * 8]);
#pragma unroll
    for (int j = 0; j < 4; ++j)
      async_cp16(srcB[j] + kc_ * 64, &Bs[bsel][(w * 256 + j * 64) * 8]);
  };

  f32x4 acc[8];
#pragma unroll
  for (int n = 0; n < 8; ++n) acc[n] = zero4();

  stage(0, 0);
  for (int kc = 0; kc < 4; ++kc) {
    int buf = kc & 1;
    if (kc < 3) {
      stage(kc + 1, buf ^ 1);
      asm volatile("s_waitcnt vmcnt(6)" ::: "memory");
    } else {
      asm volatile("s_waitcnt vmcnt(0)" ::: "memory");
    }
    __builtin_amdgcn_s_barrier();
#pragma unroll
    for (int kc2 = 0; kc2 < 2; ++kc2) {
      short8 a = *(const short8*)&As[buf][(w * 16 + i) * 64 + (((kc2 * 4 + grp) ^ (i & 7)) * 8)];
#pragma unroll
      for (int n = 0; n < 8; ++n) {
        short8 bf = *(const short8*)&Bs[buf][(n * 16 + i) * 64 + (((kc2 * 4 + grp) ^ (i & 7)) * 8)];
        acc[n] = __builtin_amdgcn_mfma_f32_16x16x32_bf16(a, bf, acc[n], 0, 0, 0);
      }
    }
    __builtin_amdgcn_s_barrier();
  }
#pragma unroll
  for (int r = 0; r < 4; ++r) {
    int t = r0 + w * 16 + grp * 4 + r;
    const float* cr = cosT + (size_t)t * 128;
    const float* sr = sinT + (size_t)t * 128;
#pragma unroll
    for (int n = 0; n < 8; ++n) {
      int d = n * 16 + i;
      float x = acc[n][r];
      float xp = acc[n ^ 4][r];
      float rot = (n < 4) ? -xp : xp;
      float val = (x * cr[d] + rot * sr[d]) * oscale;
      short bv = f2bf(val);
      if (vmode) dst[(size_t)d * TSEQ + t] = bv;
      else       dst[(size_t)t * DH + d] = bv;
    }
  }
}

// ------------------------------------------------------------------
// attn (NEW): per-wave independent jobs, direct-L2 K/V reads, no block
// barriers. Wave owns 32 q-rows (2 q-frags -> every K/V fragment feeds
// 2 MFMAs). Waves 0-3: q-tile qp; waves 4-7: q-tile 15-qp -> each SIMD
// gets one heavy + one light wave (32-34 iters const, no scheduler
// assumptions). Swapped QK^T lane-local softmax; P via 4.5KB/wave LDS.
// ------------------------------------------------------------------
__global__ __launch_bounds__(512, 2) void attn_kernel(
    const short* __restrict__ Qr, const short* __restrict__ Kr,
    const short* __restrict__ Vt, short* __restrict__ Oa) {
  __shared__ __attribute__((aligned(16))) short Ps[8][32 * 72];  // 36KB
  int tid = threadIdx.x, lane = tid & 63, w = tid >> 6;
  int i = lane & 15, grp = lane >> 4;
  int b = blockIdx.x;
  int hk = b & 7, rr_ = b >> 3, qp = rr_ & 7, hq = rr_ >> 3;
  int h = hk * 4 + hq;
  int qt = (w < 4) ? qp : (15 - qp);
  int q0 = qt * 128 + (w & 3) * 32;
  const short* Qh = Qr + (size_t)h * TSEQ * DH;
  const short* Kh = Kr + (size_t)hk * TSEQ * DH;
  const short* Vh = Vt + (size_t)hk * DH * TSEQ;
  short* Psw = &Ps[w][0];

  short8 qf[2][4];
#pragma unroll
  for (int qr = 0; qr < 2; ++qr)
#pragma unroll
    for (int c = 0; c < 4; ++c)
      qf[qr][c] = *(const short8*)&Qh[(size_t)(q0 + qr * 16 + i) * DH + c * 32 + grp * 8];

  f32x4 oacc[2][8];
#pragma unroll
  for (int qr = 0; qr < 2; ++qr)
#pragma unroll
    for (int n = 0; n < 8; ++n) oacc[qr][n] = zero4();
  float mr0 = -3.0e38f, mr1 = -3.0e38f, ls0 = 0.f, ls1 = 0.f;

  int nt = ((q0 + 31) >> 6) + 1;
  for (int kt = 0; kt < nt; ++kt) {
    int kv0 = kt * 64;
    const short* Kt = Kh + (size_t)kv0 * DH;
    // ---- QK^T (swapped), kb c-pipelined from L2; each kb feeds 2 MFMAs
    f32x4 sacc[2][4];
#pragma unroll
    for (int qr = 0; qr < 2; ++qr)
#pragma unroll
      for (int n = 0; n < 4; ++n) sacc[qr][n] = zero4();
    short8 kb0[4], kb1[4];
#pragma unroll
    for (int n = 0; n < 4; ++n)
      kb0[n] = *(const short8*)&Kt[(size_t)(n * 16 + i) * DH + grp * 8];
#pragma unroll
    for (int c = 0; c < 4; ++c) {
      if (c < 3) {
#pragma unroll
        for (int n = 0; n < 4; ++n)
          kb1[n] = *(const short8*)&Kt[(size_t)(n * 16 + i) * DH + (c + 1) * 32 + grp * 8];
      }
#pragma unroll
      for (int n = 0; n < 4; ++n) {
        sacc[0][n] = __builtin_amdgcn_mfma_f32_16x16x32_bf16(kb0[n], qf[0][c], sacc[0][n], 0, 0, 0);
        sacc[1][n] = __builtin_amdgcn_mfma_f32_16x16x32_bf16(kb0[n], qf[1][c], sacc[1][n], 0, 0, 0);
      }
#pragma unroll
      for (int n = 0; n < 4; ++n) kb0[n] = kb1[n];
    }
    // ---- issue V loads for kc=0 early (latency hides under softmax)
    short8 vb0[8];
#pragma unroll
    for (int n = 0; n < 8; ++n)
      vb0[n] = *(const short8*)&Vh[(size_t)(n * 16 + i) * TSEQ + kv0 + grp * 8];
    // ---- causal mask (last tile only; 32-row span never crosses a 64-tile)
    if (kt == nt - 1) {
#pragma unroll
      for (int qr = 0; qr < 2; ++qr) {
        int qq = q0 + qr * 16 + i;
#pragma unroll
        for (int n = 0; n < 4; ++n)
#pragma unroll
          for (int r = 0; r < 4; ++r) {
            int kk = kv0 + n * 16 + grp * 4 + r;
            if (kk > qq) sacc[qr][n][r] = -3.0e38f;
          }
      }
    }
    // ---- lane-local softmax (2 q-rows per lane; 2 shfl per row)
    float mn0 = sacc[0][0][0], mn1 = sacc[1][0][0];
#pragma unroll
    for (int n = 0; n < 4; ++n)
#pragma unroll
      for (int r = 0; r < 4; ++r) {
        mn0 = fmaxf(mn0, sacc[0][n][r]);
        mn1 = fmaxf(mn1, sacc[1][n][r]);
      }
    mn0 = fmaxf(mn0, __shfl_xor(mn0, 16)); mn0 = fmaxf(mn0, __shfl_xor(mn0, 32));
    mn1 = fmaxf(mn1, __shfl_xor(mn1, 16)); mn1 = fmaxf(mn1, __shfl_xor(mn1, 32));
    if (__any(((mn0 > mr0 + 8.0f) || (mn1 > mr1 + 8.0f)) ? 1 : 0)) {
      float mx0 = fmaxf(mr0, mn0), mx1 = fmaxf(mr1, mn1);
      float sf0 = __expf(mr0 - mx0), sf1 = __expf(mr1 - mx1);
      mr0 = mx0; mr1 = mx1; ls0 *= sf0; ls1 *= sf1;
#pragma unroll
      for (int r = 0; r < 4; ++r) {
        float f0 = __shfl(sf0, grp * 4 + r);
        float f1 = __shfl(sf1, grp * 4 + r);
#pragma unroll
        for (int n = 0; n < 8; ++n) { oacc[0][n][r] *= f0; oacc[1][n][r] *= f1; }
      }
    }
    // ---- P = exp(s-m), packed b64 stores to per-wave LDS
#pragma unroll
    for (int qr = 0; qr < 2; ++qr) {
      float mm = qr ? mr1 : mr0;
      float lsv = 0.f;
#pragma unroll
      for (int n = 0; n < 4; ++n) {
        float e0 = __expf(sacc[qr][n][0] - mm);
        float e1 = __expf(sacc[qr][n][1] - mm);
        float e2 = __expf(sacc[qr][n][2] - mm);
        float e3 = __expf(sacc[qr][n][3] - mm);
        lsv += (e0 + e1) + (e2 + e3);
        unsigned lo, hi;
        asm("v_cvt_pk_bf16_f32 %0, %1, %2" : "=v"(lo) : "v"(e0), "v"(e1));
        asm("v_cvt_pk_bf16_f32 %0, %1, %2" : "=v"(hi) : "v"(e2), "v"(e3));
        *(unsigned long long*)&Psw[(qr * 16 + i) * 72 + n * 16 + grp * 4] =
            ((unsigned long long)hi << 32) | lo;
      }
      if (qr) ls1 += lsv; else ls0 += lsv;
    }
    // ---- O += P V (vb kc=1 loaded under kc=0 MFMAs)
    short8 vb1[8];
#pragma unroll
    for (int n = 0; n < 8; ++n)
      vb1[n] = *(const short8*)&Vh[(size_t)(n * 16 + i) * TSEQ + kv0 + 32 + grp * 8];
    {
      short8 pa0 = *(const short8*)&Psw[(0 * 16 + i) * 72 + grp * 8];
      short8 pa1 = *(const short8*)&Psw[(1 * 16 + i) * 72 + grp * 8];
#pragma unroll
      for (int n = 0; n < 8; ++n) {
        oacc[0][n] = __builtin_amdgcn_mfma_f32_16x16x32_bf16(pa0, vb0[n], oacc[0][n], 0, 0, 0);
        oacc[1][n] = __builtin_amdgcn_mfma_f32_16x16x32_bf16(pa1, vb0[n], oacc[1][n], 0, 0, 0);
      }
      pa0 = *(const short8*)&Psw[(0 * 16 + i) * 72 + 32 + grp * 8];
      pa1 = *(const short8*)&Psw[(1 * 16 + i) * 72 + 32 + grp * 8];
#pragma unroll
      for (int n = 0; n < 8; ++n) {
        oacc[0][n] = __builtin_amdgcn_mfma_f32_16x16x32_bf16(pa0, vb1[n], oacc[0][n], 0, 0, 0);
        oacc[1][n] = __builtin_amdgcn_mfma_f32_16x16x32_bf16(pa1, vb1[n], oacc[1][n], 0, 0, 0);
      }
    }
  }
  // ---- finalize
  ls0 += __shfl_xor(ls0, 16); ls0 += __shfl_xor(ls0, 32);
  ls1 += __shfl_xor(ls1, 16); ls1 += __shfl_xor(ls1, 32);
  float iv0 = 1.0f / ls0, iv1 = 1.0f / ls1;
#pragma unroll
  for (int r = 0; r < 4; ++r) {
    float v0 = __shfl(iv0, grp * 4 + r);
    float v1 = __shfl(iv1, grp * 4 + r);
    int t0 = q0 + grp * 4 + r, t1 = q0 + 16 + grp * 4 + r;
#pragma unroll
    for (int n = 0; n < 8; ++n) {
      int d = h * 128 + n * 16 + i;
      Oa[(size_t)t0 * 4096 + d] = f2bf(oacc[0][n][r] * v0);
      Oa[(size_t)t1 * 4096 + d] = f2bf(oacc[1][n][r] * v1);
    }
  }
}

// ------------------------------------------------------------------
// outproj (proven r7): split-K=4, DMA dbuf.
// ------------------------------------------------------------------
__global__ __launch_bounds__(256) void outproj_kernel(
    const short* __restrict__ Oa, const short* __restrict__ WoT,
    float* __restrict__ Opart) {
  __shared__ __attribute__((aligned(16))) short As[2][128 * 64];
  __shared__ __attribute__((aligned(16))) short Bs[2][64 * 64];
  int tid = threadIdx.x, lane = tid & 63, w = tid >> 6;
  int i = lane & 15, grp = lane >> 4;
  int m0 = blockIdx.x * 128, n0 = blockIdx.y * 64, z = blockIdx.z;

  const short* srcA[4];
#pragma unroll
  for (int j = 0; j < 4; ++j) {
    int ci = w * 256 + j * 64 + lane;
    int row = ci >> 3, c = ci & 7;
    srcA[j] = Oa + (size_t)(m0 + row) * 4096 + (size_t)z * 1024 + ((c ^ (row & 7)) << 3);
  }
  const short* srcB[2];
#pragma unroll
  for (int j = 0; j < 2; ++j) {
    int ci = w * 128 + j * 64 + lane;
    int row = ci >> 3, c = ci & 7;
    srcB[j] = WoT + (size_t)(n0 + row) * 4096 + (size_t)z * 1024 + ((c ^ (row & 7)) << 3);
  }
  auto stage = [&](int kc_, int bsel) {
#pragma unroll
    for (int j = 0; j < 4; ++j)
      async_cp16(srcA[j] + kc_ * 64, &As[bsel][(w * 256 + j * 64) * 8]);
#pragma unroll
    for (int j = 0; j < 2; ++j)
      async_cp16(srcB[j] + kc_ * 64, &Bs[bsel][(w * 128 + j * 64) * 8]);
  };

  f32x4 acc[2][4];
#pragma unroll
  for (int mf = 0; mf < 2; ++mf)
#pragma unroll
    for (int nf = 0; nf < 4; ++nf) acc[mf][nf] = zero4();

  stage(0, 0);
  for (int kc = 0; kc < 16; ++kc) {
    int buf = kc & 1;
    if (kc < 15) {
      stage(kc + 1, buf ^ 1);
      asm volatile("s_waitcnt vmcnt(6)" ::: "memory");
    } else {
      asm volatile("s_waitcnt vmcnt(0)" ::: "memory");
    }
    __builtin_amdgcn_s_barrier();
#pragma unroll
    for (int kc2 = 0; kc2 < 2; ++kc2) {
#pragma unroll
      for (int mf = 0; mf < 2; ++mf) {
        short8 a = *(const short8*)&As[buf][(w * 32 + mf * 16 + i) * 64 + (((kc2 * 4 + grp) ^ (i & 7)) * 8)];
#pragma unroll
        for (int nf = 0; nf < 4; ++nf) {
          short8 bb = *(const short8*)&Bs[buf][(nf * 16 + i) * 64 + (((kc2 * 4 + grp) ^ (i & 7)) * 8)];
          acc[mf][nf] = __builtin_amdgcn_mfma_f32_16x16x32_bf16(a, bb, acc[mf][nf], 0, 0, 0);
        }
      }
    }
    __builtin_amdgcn_s_barrier();
  }
  float* dst = Opart + (size_t)z * (TSEQ * 256);
#pragma unroll
  for (int mf = 0; mf < 2; ++mf)
#pragma unroll
    for (int r = 0; r < 4; ++r) {
      int t = m0 + w * 32 + mf * 16 + grp * 4 + r;
#pragma unroll
      for (int nf = 0; nf < 4; ++nf)
        dst[(size_t)t * 256 + n0 + nf * 16 + i] = acc[mf][nf][r];
    }
}

// ------------------------------------------------------------------
__global__ __launch_bounds__(256) void reduce_kernel(
    const float* __restrict__ Opart, float* __restrict__ out) {
  int gid = blockIdx.x * 256 + threadIdx.x;
  int i4 = gid * 4;
  f32x4 s = *(const f32x4*)&Opart[i4];
#pragma unroll
  for (int z = 1; z < 4; ++z) {
    f32x4 p = *(const f32x4*)&Opart[(size_t)z * (TSEQ * 256) + i4];
    s[0] += p[0]; s[1] += p[1]; s[2] += p[2]; s[3] += p[3];
  }
  *(f32x4*)&out[i4] = s;
}

// ------------------------------------------------------------------
extern "C" void kernel_launch(void* const* d_in, const int* in_sizes, int n_in,
                              void* d_out, int out_size, void* d_ws, size_t ws_size,
                              hipStream_t stream) {
  const float* q  = (const float*)d_in[0];
  const float* k  = (const float*)d_in[1];
  const float* v  = (const float*)d_in[2];
  // d_in[3] = causal mask (always tril) -- applied analytically
  const float* Wq = (const float*)d_in[4];
  const float* Wk = (const float*)d_in[5];
  const float* Wv = (const float*)d_in[6];
  const float* Wo = (const float*)d_in[7];
  float* out = (float*)d_out;

  char* p = (char*)d_ws;
  auto take = [&](size_t nbytes) {
    char* r = p; p += (nbytes + 255) & ~(size_t)255; return r;
  };
  short* qkv  = (short*)take(3ull * TSEQ * 256 * 2);
  short* WqT  = (short*)take(4096ull * 256 * 2);
  short* WkT  = (short*)take(1024ull * 256 * 2);
  short* WvT  = (short*)take(1024ull * 256 * 2);
  short* WoT  = (short*)take(256ull * 4096 * 2);
  float* cosT = (float*)take((size_t)TSEQ * 128 * 4);
  float* sinT = (float*)take((size_t)TSEQ * 128 * 4);
  short* Qr   = (short*)take((size_t)NHQ * TSEQ * DH * 2);
  short* Kr   = (short*)take((size_t)NHK * TSEQ * DH * 2);
  short* Vt   = (short*)take((size_t)NHK * TSEQ * DH * 2);
  short* Oa   = (short*)take((size_t)TSEQ * 4096 * 2);
  // split-K partials alias Qr (dead after attn_kernel; same stream order).
  float* Opart = (float*)Qr;

  hipLaunchKernelGGL(prep_transpose_kernel, dim3(2432), dim3(256), 0, stream,
                     q, k, v, qkv, cosT, sinT,
                     Wq, Wk, Wv, Wo, WqT, WkT, WvT, WoT);
  hipLaunchKernelGGL(proj_kernel, dim3(32, 48), dim3(256), 0, stream,
                     qkv, WqT, WkT, WvT, cosT, sinT, Qr, Kr, Vt);
  hipLaunchKernelGGL(attn_kernel, dim3(256), dim3(512), 0, stream,
                     Qr, Kr, Vt, Oa);
  hipLaunchKernelGGL(outproj_kernel, dim3(16, 4, 4), dim3(256), 0, stream,
                     Oa, WoT, Opart);
  hipLaunchKernelGGL(reduce_kernel, dim3(512), dim3(256), 0, stream,
                     Opart, out);
}

// Round 10
// 200.566 us; speedup vs baseline: 1.2547x; 1.2547x over previous
//
#include <hip/hip_runtime.h>
#include <hip/hip_bf16.h>
#include <math.h>

#define TSEQ 2048
#define NHQ 32
#define NHK 8
#define DH 128

typedef __attribute__((ext_vector_type(8))) short short8;
typedef __attribute__((ext_vector_type(4))) float f32x4;
typedef __attribute__((ext_vector_type(4))) short s16x4;

__device__ __forceinline__ short f2bf(float f) {
  union { float f; unsigned u; } v; v.f = f;
  unsigned r = v.u + 0x7fffu + ((v.u >> 16) & 1u);
  return (short)(r >> 16);
}

__device__ __forceinline__ f32x4 zero4() {
  f32x4 z; z[0] = 0.f; z[1] = 0.f; z[2] = 0.f; z[3] = 0.f; return z;
}

// async 16B global->LDS DMA (LDS dest wave-uniform base + lane*16).
__device__ __forceinline__ void async_cp16(const short* g, short* l) {
  __builtin_amdgcn_global_load_lds(
      (const __attribute__((address_space(1))) unsigned int*)g,
      (__attribute__((address_space(3))) unsigned int*)l, 16, 0, 0);
}

// ------------------------------------------------------------------
// prep+transpose fused (proven r7)
// ------------------------------------------------------------------
__global__ __launch_bounds__(256) void prep_transpose_kernel(
    const float* __restrict__ q, const float* __restrict__ k,
    const float* __restrict__ v, short* __restrict__ qkv,
    float* __restrict__ cosT, float* __restrict__ sinT,
    const float* __restrict__ Wq, const float* __restrict__ Wk,
    const float* __restrict__ Wv, const float* __restrict__ Wo,
    short* __restrict__ WqT, short* __restrict__ WkT,
    short* __restrict__ WvT, short* __restrict__ WoT) {
  __shared__ short tl[64][65];
  int bx = blockIdx.x, tid = threadIdx.x;
  if (bx < 1792) {
    int gid = bx * 256 + tid;
    if (gid < 393216) {
      int i4 = gid * 4;
      const float* src = (i4 < 524288) ? (q + i4)
                       : (i4 < 1048576 ? (k + i4 - 524288) : (v + i4 - 1048576));
      float f0 = src[0], f1 = src[1], f2 = src[2], f3 = src[3];
      s16x4 o; o[0] = f2bf(f0); o[1] = f2bf(f1); o[2] = f2bf(f2); o[3] = f2bf(f3);
      *(s16x4*)&qkv[i4] = o;
    } else if (gid < 458752) {
      int idx = (gid - 393216) * 4;
      int t = idx >> 7, d0 = idx & 127;
      float pos = (float)(8192 - TSEQ + t);
#pragma unroll
      for (int jj = 0; jj < 4; ++jj) {
        int d = d0 + jj;
        float inv = exp2f(-0.10381025296522977f * (float)d);
        float f = pos * inv;
        cosT[t * 128 + d] = cosf(f);
        sinT[t * 128 + d] = sinf(f);
      }
    }
    return;
  }
  int b = bx - 1792;
  const float* S; short* D; int K, N, tr, tc;
  if (b < 256)      { S = Wq; D = WqT; K = 256;  N = 4096; tr = b >> 6;        tc = b & 63; }
  else if (b < 320) { S = Wk; D = WkT; K = 256;  N = 1024; int t = b - 256; tr = t >> 4; tc = t & 15; }
  else if (b < 384) { S = Wv; D = WvT; K = 256;  N = 1024; int t = b - 320; tr = t >> 4; tc = t & 15; }
  else              { S = Wo; D = WoT; K = 4096; N = 256;  int t = b - 384; tr = t >> 2; tc = t & 3; }
  int k0 = tr * 64, n0 = tc * 64;
#pragma unroll
  for (int it = 0; it < 4; ++it) {
    int r = it * 16 + (tid >> 4), c = (tid & 15) * 4;
    const float* s = &S[(size_t)(k0 + r) * N + n0 + c];
    tl[r][c + 0] = f2bf(s[0]); tl[r][c + 1] = f2bf(s[1]);
    tl[r][c + 2] = f2bf(s[2]); tl[r][c + 3] = f2bf(s[3]);
  }
  __syncthreads();
#pragma unroll
  for (int it = 0; it < 4; ++it) {
    int rr = it * 16 + (tid >> 4), cc = (tid & 15) * 4;
    s16x4 o;
    o[0] = tl[cc + 0][rr]; o[1] = tl[cc + 1][rr];
    o[2] = tl[cc + 2][rr]; o[3] = tl[cc + 3][rr];
    *(s16x4*)&D[(size_t)(n0 + rr) * K + k0 + cc] = o;
  }
}

// ------------------------------------------------------------------
// proj (proven r7): DMA-staged dbuf, RoPE epilogue, Q pre-scaled.
// ------------------------------------------------------------------
#define SCALE 0.08838834764831845f

__global__ __launch_bounds__(256) void proj_kernel(
    const short* __restrict__ qkv,
    const short* __restrict__ WqT, const short* __restrict__ WkT,
    const short* __restrict__ WvT,
    const float* __restrict__ cosT, const float* __restrict__ sinT,
    short* __restrict__ Qr, short* __restrict__ Kr, short* __restrict__ Vt) {
  __shared__ __attribute__((aligned(16))) short As[2][64 * 64];
  __shared__ __attribute__((aligned(16))) short Bs[2][128 * 64];
  int tid = threadIdx.x, lane = tid & 63, w = tid >> 6;
  int i = lane & 15, grp = lane >> 4;
  int bh = blockIdx.y, r0 = blockIdx.x * 64;
  const short* X; const short* Wt; short* dst; int vmode = 0;
  float oscale = 1.0f;
  if (bh < 32)      { X = qkv;                Wt = WqT + bh * (128 * 256);        dst = Qr + (size_t)bh * TSEQ * DH; oscale = SCALE; }
  else if (bh < 40) { X = qkv + TSEQ * 256;   Wt = WkT + (bh - 32) * (128 * 256); dst = Kr + (size_t)(bh - 32) * TSEQ * DH; }
  else              { X = qkv + 2 * TSEQ * 256; Wt = WvT + (bh - 40) * (128 * 256); dst = Vt + (size_t)(bh - 40) * DH * TSEQ; vmode = 1; }

  const short* srcA[2];
#pragma unroll
  for (int j = 0; j < 2; ++j) {
    int ci = w * 128 + j * 64 + lane;
    int row = ci >> 3, c = ci & 7;
    srcA[j] = X + (size_t)(r0 + row) * 256 + ((c ^ (row & 7)) << 3);
  }
  const short* srcB[4];
#pragma unroll
  for (int j = 0; j < 4; ++j) {
    int ci = w * 256 + j * 64 + lane;
    int row = ci >> 3, c = ci & 7;
    srcB[j] = Wt + (size_t)row * 256 + ((c ^ (row & 7)) << 3);
  }
  auto stage = [&](int kc_, int bsel) {
#pragma unroll
    for (int j = 0; j < 2; ++j)
      async_cp16(srcA[j] + kc_ * 64, &As[bsel][(w * 128 + j * 64) * 8]);
#pragma unroll
    for (int j = 0; j < 4; ++j)
      async_cp16(srcB[j] + kc_ * 64, &Bs[bsel][(w * 256 + j * 64) * 8]);
  };

  f32x4 acc[8];
#pragma unroll
  for (int n = 0; n < 8; ++n) acc[n] = zero4();

  stage(0, 0);
  for (int kc = 0; kc < 4; ++kc) {
    int buf = kc & 1;
    if (kc < 3) {
      stage(kc + 1, buf ^ 1);
      asm volatile("s_waitcnt vmcnt(6)" ::: "memory");
    } else {
      asm volatile("s_waitcnt vmcnt(0)" ::: "memory");
    }
    __builtin_amdgcn_s_barrier();
#pragma unroll
    for (int kc2 = 0; kc2 < 2; ++kc2) {
      short8 a = *(const short8*)&As[buf][(w * 16 + i) * 64 + (((kc2 * 4 + grp) ^ (i & 7)) * 8)];
#pragma unroll
      for (int n = 0; n < 8; ++n) {
        short8 bf = *(const short8*)&Bs[buf][(n * 16 + i) * 64 + (((kc2 * 4 + grp) ^ (i & 7)) * 8)];
        acc[n] = __builtin_amdgcn_mfma_f32_16x16x32_bf16(a, bf, acc[n], 0, 0, 0);
      }
    }
    __builtin_amdgcn_s_barrier();
  }
#pragma unroll
  for (int r = 0; r < 4; ++r) {
    int t = r0 + w * 16 + grp * 4 + r;
    const float* cr = cosT + (size_t)t * 128;
    const float* sr = sinT + (size_t)t * 128;
#pragma unroll
    for (int n = 0; n < 8; ++n) {
      int d = n * 16 + i;
      float x = acc[n][r];
      float xp = acc[n ^ 4][r];
      float rot = (n < 4) ? -xp : xp;
      float val = (x * cr[d] + rot * sr[d]) * oscale;
      short bv = f2bf(val);
      if (vmode) dst[(size_t)d * TSEQ + t] = bv;
      else       dst[(size_t)t * DH + d] = bv;
    }
  }
}

// ------------------------------------------------------------------
// attn: r7 structure (QBLK=128, 8 waves, LDS-staged dbuf K/V, swapped
// QK^T lane-local softmax, defer-max, setprio) with two fixes:
//  - P buffer stride 72->64 + XOR chunk-swizzle: LDS 82->80KB
//    -> 2 blocks/CU co-resident -> phase-offset VALU/MFMA overlap.
//  - grid 512 (un-paired), heavy-first (LPT), hk=b&7 pinned to XCD.
// ------------------------------------------------------------------
__global__ __launch_bounds__(512, 2) void attn_kernel(
    const short* __restrict__ Qr, const short* __restrict__ Kr,
    const short* __restrict__ Vt, short* __restrict__ Oa) {
  __shared__ __attribute__((aligned(16))) short Ks[2][64 * 128]; // 32KB
  __shared__ __attribute__((aligned(16))) short Vs[2][128 * 64]; // 32KB
  __shared__ __attribute__((aligned(16))) short Ps[8][16 * 64];  // 16KB (swizzled)
  int tid = threadIdx.x, lane = tid & 63, w = tid >> 6;  // w in 0..7
  int i = lane & 15, grp = lane >> 4;
  int b = blockIdx.x;
  int hk = b & 7, t_ = b >> 3, hq = t_ & 3, qrank = t_ >> 2;
  int qt = 15 - qrank;                  // heavy-first
  int h = hk * 4 + hq;
  int q0 = qt * 128;
  const short* Qh = Qr + (size_t)h * TSEQ * DH;
  const short* Kh = Kr + (size_t)hk * TSEQ * DH;
  const short* Vh = Vt + (size_t)hk * DH * TSEQ;
  short* Psw = &Ps[w][0];

  // hoisted per-lane DMA source bases
  const short* kst[2]; const short* vst[2];
#pragma unroll
  for (int hf = 0; hf < 2; ++hf) {
    int ci = hf * 512 + w * 64 + lane;
    int rk = ci >> 4, ck = ci & 15;
    kst[hf] = Kh + (size_t)rk * DH + ((ck ^ (rk & 15)) << 3);
    int rv = ci >> 3, cv = ci & 7;
    vst[hf] = Vh + (size_t)rv * TSEQ + ((cv ^ (rv & 7)) << 3);
  }

  int qq = q0 + w * 16 + i;             // this lane's q-row (swapped layout)
  short8 qf[4];
#pragma unroll
  for (int c = 0; c < 4; ++c)
    qf[c] = *(const short8*)&Qh[(size_t)qq * DH + c * 32 + grp * 8];

  f32x4 oacc[8];
#pragma unroll
  for (int n = 0; n < 8; ++n) oacc[n] = zero4();
  float mrow = -3.0e38f, lsum = 0.0f;

  int nt = 2 * qt + 2;
  int wave_max_row = q0 + w * 16 + 15;

  auto stage = [&](int kt_, int bsel) {
    int kv0_ = kt_ * 64;
    async_cp16(kst[0] + (size_t)kv0_ * DH, &Ks[bsel][w * 512]);
    async_cp16(kst[1] + (size_t)kv0_ * DH, &Ks[bsel][4096 + w * 512]);
    async_cp16(vst[0] + kv0_, &Vs[bsel][w * 512]);
    async_cp16(vst[1] + kv0_, &Vs[bsel][4096 + w * 512]);
  };

  stage(0, 0);
  for (int kt = 0; kt < nt; ++kt) {
    int kv0 = kt * 64;
    int buf = kt & 1;
    if (kt + 1 < nt) {
      stage(kt + 1, buf ^ 1);
      asm volatile("s_waitcnt vmcnt(4)" ::: "memory");
    } else {
      asm volatile("s_waitcnt vmcnt(0)" ::: "memory");
    }
    __builtin_amdgcn_s_barrier();
    if (kv0 <= wave_max_row) {
      const short* Kb = &Ks[buf][0];
      const short* Vb = &Vs[buf][0];
      // S^T = K Q^T: D[row=kv=n*16+grp*4+r][col=q=i]
      f32x4 sacc[4];
#pragma unroll
      for (int n = 0; n < 4; ++n) sacc[n] = zero4();
      __builtin_amdgcn_s_setprio(1);
#pragma unroll
      for (int c = 0; c < 4; ++c) {
#pragma unroll
        for (int n = 0; n < 4; ++n) {
          short8 kb = *(const short8*)&Kb[(n * 16 + i) * 128 + (((c * 4 + grp) ^ i) * 8)];
          sacc[n] = __builtin_amdgcn_mfma_f32_16x16x32_bf16(kb, qf[c], sacc[n], 0, 0, 0);
        }
      }
      __builtin_amdgcn_s_setprio(0);
      bool diag = (kt >= nt - 2);
      float p_[4][4];
#pragma unroll
      for (int n = 0; n < 4; ++n)
#pragma unroll
        for (int r = 0; r < 4; ++r) {
          float s = sacc[n][r];
          if (diag) {
            int kk = kv0 + n * 16 + grp * 4 + r;
            if (kk > qq) s = -3.0e38f;
          }
          p_[n][r] = s;
        }
      float mnew = p_[0][0];
#pragma unroll
      for (int n = 0; n < 4; ++n)
#pragma unroll
        for (int r = 0; r < 4; ++r) mnew = fmaxf(mnew, p_[n][r]);
      mnew = fmaxf(mnew, __shfl_xor(mnew, 16));
      mnew = fmaxf(mnew, __shfl_xor(mnew, 32));
      if (__any((mnew > mrow + 8.0f) ? 1 : 0)) {
        float mn = fmaxf(mrow, mnew);
        float sfv = __expf(mrow - mn);
        mrow = mn;
        lsum *= sfv;
        float sf0 = __shfl(sfv, grp * 4 + 0);
        float sf1 = __shfl(sfv, grp * 4 + 1);
        float sf2 = __shfl(sfv, grp * 4 + 2);
        float sf3 = __shfl(sfv, grp * 4 + 3);
#pragma unroll
        for (int n = 0; n < 8; ++n) {
          oacc[n][0] *= sf0; oacc[n][1] *= sf1;
          oacc[n][2] *= sf2; oacc[n][3] *= sf3;
        }
      }
      // P = exp(s-m): packed b64 store, chunk-swizzled (stride 64)
#pragma unroll
      for (int n = 0; n < 4; ++n) {
        float e0 = __expf(p_[n][0] - mrow);
        float e1 = __expf(p_[n][1] - mrow);
        float e2 = __expf(p_[n][2] - mrow);
        float e3 = __expf(p_[n][3] - mrow);
        lsum += (e0 + e1) + (e2 + e3);
        unsigned lo, hi;
        asm("v_cvt_pk_bf16_f32 %0, %1, %2" : "=v"(lo) : "v"(e0), "v"(e1));
        asm("v_cvt_pk_bf16_f32 %0, %1, %2" : "=v"(hi) : "v"(e2), "v"(e3));
        // kv chunk c = 2n + (grp>>1); swizzled c^(i&7); half-offset (grp&1)*4
        *(unsigned long long*)&Psw[i * 64 + (((2 * n + (grp >> 1)) ^ (i & 7)) * 8) + (grp & 1) * 4] =
            ((unsigned long long)hi << 32) | lo;
      }
      // O += P V
      __builtin_amdgcn_s_setprio(1);
#pragma unroll
      for (int kc = 0; kc < 2; ++kc) {
        short8 pa = *(const short8*)&Psw[i * 64 + (((kc * 4 + grp) ^ (i & 7)) * 8)];
#pragma unroll
        for (int n = 0; n < 8; ++n) {
          short8 vb = *(const short8*)&Vb[(n * 16 + i) * 64 + (((kc * 4 + grp) ^ (i & 7)) * 8)];
          oacc[n] = __builtin_amdgcn_mfma_f32_16x16x32_bf16(pa, vb, oacc[n], 0, 0, 0);
        }
      }
      __builtin_amdgcn_s_setprio(0);
    }
    __builtin_amdgcn_s_barrier();
  }
  // finalize
  lsum += __shfl_xor(lsum, 16);
  lsum += __shfl_xor(lsum, 32);
  float inv[4];
#pragma unroll
  for (int r = 0; r < 4; ++r) inv[r] = 1.0f / __shfl(lsum, grp * 4 + r);
#pragma unroll
  for (int r = 0; r < 4; ++r) {
    int t = q0 + w * 16 + grp * 4 + r;
#pragma unroll
    for (int n = 0; n < 8; ++n) {
      int d = n * 16 + i;
      Oa[(size_t)t * 4096 + h * 128 + d] = f2bf(oacc[n][r] * inv[r]);
    }
  }
}

// ------------------------------------------------------------------
// outproj: split-K=4, DMA dbuf, atomic-accumulate into zeroed out
// (drops the separate reduce dispatch + Opart traffic).
// ------------------------------------------------------------------
__global__ __launch_bounds__(256) void outproj_kernel(
    const short* __restrict__ Oa, const short* __restrict__ WoT,
    float* __restrict__ out) {
  __shared__ __attribute__((aligned(16))) short As[2][128 * 64];
  __shared__ __attribute__((aligned(16))) short Bs[2][64 * 64];
  int tid = threadIdx.x, lane = tid & 63, w = tid >> 6;
  int i = lane & 15, grp = lane >> 4;
  int m0 = blockIdx.x * 128, n0 = blockIdx.y * 64, z = blockIdx.z;

  const short* srcA[4];
#pragma unroll
  for (int j = 0; j < 4; ++j) {
    int ci = w * 256 + j * 64 + lane;
    int row = ci >> 3, c = ci & 7;
    srcA[j] = Oa + (size_t)(m0 + row) * 4096 + (size_t)z * 1024 + ((c ^ (row & 7)) << 3);
  }
  const short* srcB[2];
#pragma unroll
  for (int j = 0; j < 2; ++j) {
    int ci = w * 128 + j * 64 + lane;
    int row = ci >> 3, c = ci & 7;
    srcB[j] = WoT + (size_t)(n0 + row) * 4096 + (size_t)z * 1024 + ((c ^ (row & 7)) << 3);
  }
  auto stage = [&](int kc_, int bsel) {
#pragma unroll
    for (int j = 0; j < 4; ++j)
      async_cp16(srcA[j] + kc_ * 64, &As[bsel][(w * 256 + j * 64) * 8]);
#pragma unroll
    for (int j = 0; j < 2; ++j)
      async_cp16(srcB[j] + kc_ * 64, &Bs[bsel][(w * 128 + j * 64) * 8]);
  };

  f32x4 acc[2][4];
#pragma unroll
  for (int mf = 0; mf < 2; ++mf)
#pragma unroll
    for (int nf = 0; nf < 4; ++nf) acc[mf][nf] = zero4();

  stage(0, 0);
  for (int kc = 0; kc < 16; ++kc) {
    int buf = kc & 1;
    if (kc < 15) {
      stage(kc + 1, buf ^ 1);
      asm volatile("s_waitcnt vmcnt(6)" ::: "memory");
    } else {
      asm volatile("s_waitcnt vmcnt(0)" ::: "memory");
    }
    __builtin_amdgcn_s_barrier();
#pragma unroll
    for (int kc2 = 0; kc2 < 2; ++kc2) {
#pragma unroll
      for (int mf = 0; mf < 2; ++mf) {
        short8 a = *(const short8*)&As[buf][(w * 32 + mf * 16 + i) * 64 + (((kc2 * 4 + grp) ^ (i & 7)) * 8)];
#pragma unroll
        for (int nf = 0; nf < 4; ++nf) {
          short8 bb = *(const short8*)&Bs[buf][(nf * 16 + i) * 64 + (((kc2 * 4 + grp) ^ (i & 7)) * 8)];
          acc[mf][nf] = __builtin_amdgcn_mfma_f32_16x16x32_bf16(a, bb, acc[mf][nf], 0, 0, 0);
        }
      }
    }
    __builtin_amdgcn_s_barrier();
  }
#pragma unroll
  for (int mf = 0; mf < 2; ++mf)
#pragma unroll
    for (int r = 0; r < 4; ++r) {
      int t = m0 + w * 32 + mf * 16 + grp * 4 + r;
#pragma unroll
      for (int nf = 0; nf < 4; ++nf)
        atomicAdd(&out[(size_t)t * 256 + n0 + nf * 16 + i], acc[mf][nf][r]);
    }
}

// ------------------------------------------------------------------
extern "C" void kernel_launch(void* const* d_in, const int* in_sizes, int n_in,
                              void* d_out, int out_size, void* d_ws, size_t ws_size,
                              hipStream_t stream) {
  const float* q  = (const float*)d_in[0];
  const float* k  = (const float*)d_in[1];
  const float* v  = (const float*)d_in[2];
  // d_in[3] = causal mask (always tril) -- applied analytically
  const float* Wq = (const float*)d_in[4];
  const float* Wk = (const float*)d_in[5];
  const float* Wv = (const float*)d_in[6];
  const float* Wo = (const float*)d_in[7];
  float* out = (float*)d_out;

  char* p = (char*)d_ws;
  auto take = [&](size_t nbytes) {
    char* r = p; p += (nbytes + 255) & ~(size_t)255; return r;
  };
  short* qkv  = (short*)take(3ull * TSEQ * 256 * 2);
  short* WqT  = (short*)take(4096ull * 256 * 2);
  short* WkT  = (short*)take(1024ull * 256 * 2);
  short* WvT  = (short*)take(1024ull * 256 * 2);
  short* WoT  = (short*)take(256ull * 4096 * 2);
  float* cosT = (float*)take((size_t)TSEQ * 128 * 4);
  float* sinT = (float*)take((size_t)TSEQ * 128 * 4);
  short* Qr   = (short*)take((size_t)NHQ * TSEQ * DH * 2);
  short* Kr   = (short*)take((size_t)NHK * TSEQ * DH * 2);
  short* Vt   = (short*)take((size_t)NHK * TSEQ * DH * 2);
  short* Oa   = (short*)take((size_t)TSEQ * 4096 * 2);

  hipMemsetAsync(out, 0, (size_t)out_size * sizeof(float), stream);
  hipLaunchKernelGGL(prep_transpose_kernel, dim3(2432), dim3(256), 0, stream,
                     q, k, v, qkv, cosT, sinT,
                     Wq, Wk, Wv, Wo, WqT, WkT, WvT, WoT);
  hipLaunchKernelGGL(proj_kernel, dim3(32, 48), dim3(256), 0, stream,
                     qkv, WqT, WkT, WvT, cosT, sinT, Qr, Kr, Vt);
  hipLaunchKernelGGL(attn_kernel, dim3(512), dim3(512), 0, stream,
                     Qr, Kr, Vt, Oa);
  hipLaunchKernelGGL(outproj_kernel, dim3(16, 4, 4), dim3(256), 0, stream,
                     Oa, WoT, out);
}